// Round 1
// baseline (17599.196 us; speedup 1.0000x reference)
//
#include <hip/hip_runtime.h>
#include <stdint.h>

// Problem constants
static constexpr int H    = 744;   // hidden
static constexpr int HP   = 768;   // padded hidden (48*16)
static constexpr int TT   = 256;   // timesteps
static constexpr int BB   = 256;   // batch
static constexpr int WINW = 800;   // window width (x = first H cols)
static constexpr int CCLIP = 16;
static constexpr int TOUT = 224;   // TT - 2*CCLIP
static constexpr int OUTC = 1488;  // 2*H

typedef __bf16 bf16x8 __attribute__((ext_vector_type(8)));
typedef float  f32x4  __attribute__((ext_vector_type(4)));

__device__ __forceinline__ unsigned short f2bf(float f) {
    union { float f; uint32_t u; } v; v.f = f;
    uint32_t u = v.u;
    uint32_t r = u + 0x7fffu + ((u >> 16) & 1u);   // RNE
    return (unsigned short)(r >> 16);
}
__device__ __forceinline__ float bf2f(unsigned short s) {
    union { uint32_t u; float f; } v; v.u = ((uint32_t)s) << 16;
    return v.f;
}

// ---------------- init kernels ----------------

__global__ void zero_h(unsigned short* __restrict__ hbf) {
    int i = blockIdx.x * blockDim.x + threadIdx.x;
    const int total = 4 * BB * HP;   // 2 dirs x 2 parities
    for (; i < total; i += gridDim.x * blockDim.x) hbf[i] = 0;
}

// wbf layout: [chunk][j'=g*768+i'][k'] bf16, chunk = dir*2 + part (part0=Wih, part1=Whh)
__global__ void conv_w(const float* __restrict__ wih_f, const float* __restrict__ whh_f,
                       const float* __restrict__ wih_b, const float* __restrict__ whh_b,
                       unsigned short* __restrict__ wbf) {
    const int chunk = blockIdx.y;            // 0..3
    const int jp    = blockIdx.x;            // 0..2303
    const int g = jp / HP, ip = jp % HP;
    const float* src = (chunk == 0) ? wih_f : (chunk == 1) ? whh_f : (chunk == 2) ? wih_b : whh_b;
    unsigned short* dst = wbf + ((size_t)chunk * 2304 + jp) * HP;
    const float* srow = (ip < H) ? (src + (size_t)(g * H + ip) * H) : nullptr;
    for (int k = threadIdx.x; k < HP; k += blockDim.x) {
        float v = (srow != nullptr && k < H) ? srow[k] : 0.0f;
        dst[k] = f2bf(v);
    }
}

// ---------------- fused GRU step ----------------
// Grid: (48 i-blocks, 2 b-blocks, 2 dirs), 256 threads.
// Block computes 128 b x (16 i x 3 gates), K = 744(x) + 744(h), padded to 768 each.

static constexpr int BT  = 128;  // b tile
static constexpr int KC  = 64;   // k chunk
static constexpr int LDA = 72;   // LDS stride (elements) — 144B, keeps 16B alignment, 2-way-max conflicts

__global__ __launch_bounds__(256) void gru_step(
    const float* __restrict__ windows,
    const unsigned short* __restrict__ wbf,
    unsigned short* __restrict__ hbf,
    const float* __restrict__ bih_f, const float* __restrict__ bhh_f,
    const float* __restrict__ bih_b, const float* __restrict__ bhh_b,
    float* __restrict__ out, int t)
{
    __shared__ __align__(16) unsigned short Als[BT * LDA];
    __shared__ __align__(16) unsigned short Bls[48 * LDA];

    const int tid = threadIdx.x;
    const int dir = blockIdx.z;
    const int b0  = blockIdx.y * BT;
    const int i0  = blockIdx.x * 16;
    const int tx  = dir ? (TT - 1 - t) : t;
    const int rp  = t & 1;
    const unsigned short* hin  = hbf + (size_t)(dir * 2 + rp)       * BB * HP;
    unsigned short*       hout = hbf + (size_t)(dir * 2 + (1 - rp)) * BB * HP;

    const int w32 = (tid >> 6) * 32;   // wave's 32-row sub-tile
    const int l   = tid & 63;
    const int lr  = l & 15;
    const int lq  = l >> 4;

    f32x4 acc[2][4] = {};   // [m 16-row group][r, z, n_x, n_h]

    for (int kk = 0; kk < 24; ++kk) {
        const int part = (kk >= 12) ? 1 : 0;
        const int k0   = (part ? (kk - 12) : kk) * KC;

        // ---- stage A (activations) ----
        if (!part) {
            // x from windows (fp32 -> bf16), rows b0..b0+127, cols k0..k0+63
#pragma unroll
            for (int rep = 0; rep < 8; ++rep) {
                int idx = rep * 256 + tid;
                int row = idx >> 4, c4 = idx & 15;
                int k = k0 + c4 * 4;
                float4 v = {0.f, 0.f, 0.f, 0.f};
                if (k < H)
                    v = *(const float4*)&windows[((size_t)(b0 + row) * TT + tx) * WINW + k];
                ushort4 s;
                s.x = f2bf(v.x); s.y = f2bf(v.y); s.z = f2bf(v.z); s.w = f2bf(v.w);
                *(ushort4*)&Als[row * LDA + c4 * 4] = s;
            }
        } else {
            // h (already bf16, padded cols are zero)
#pragma unroll
            for (int rep = 0; rep < 4; ++rep) {
                int idx = rep * 256 + tid;
                int row = idx >> 3, c8 = idx & 7;
                uint4 v = *(const uint4*)&hin[(size_t)(b0 + row) * HP + k0 + c8 * 8];
                *(uint4*)&Als[row * LDA + c8 * 8] = v;
            }
        }
        // ---- stage B (weights, 48 rows = 3 gates x 16 i) ----
        {
            const unsigned short* wsrc = wbf + (size_t)(dir * 2 + part) * 2304 * HP;
#pragma unroll
            for (int rep = 0; rep < 2; ++rep) {
                int idx = rep * 256 + tid;
                if (idx < 384) {
                    int jl = idx >> 3, c8 = idx & 7;
                    int jrow = (jl >> 4) * HP + i0 + (jl & 15);
                    uint4 v = *(const uint4*)&wsrc[(size_t)jrow * HP + k0 + c8 * 8];
                    *(uint4*)&Bls[jl * LDA + c8 * 8] = v;
                }
            }
        }
        __syncthreads();

        // ---- MFMA ----
#pragma unroll
        for (int ks = 0; ks < 2; ++ks) {
            int ko = ks * 32 + lq * 8;
            bf16x8 a0 = *(const bf16x8*)&Als[(w32 + lr) * LDA + ko];
            bf16x8 a1 = *(const bf16x8*)&Als[(w32 + 16 + lr) * LDA + ko];
#pragma unroll
            for (int g = 0; g < 3; ++g) {
                bf16x8 bfr = *(const bf16x8*)&Bls[(g * 16 + lr) * LDA + ko];
                int gs = (g < 2) ? g : (part ? 3 : 2);
                acc[0][gs] = __builtin_amdgcn_mfma_f32_16x16x32_bf16(a0, bfr, acc[0][gs], 0, 0, 0);
                acc[1][gs] = __builtin_amdgcn_mfma_f32_16x16x32_bf16(a1, bfr, acc[1][gs], 0, 0, 0);
            }
        }
        __syncthreads();
    }

    // ---- epilogue: gates, h update, fused output ----
    const int ig = i0 + lr;
    if (ig < H) {
        const float* bih = dir ? bih_b : bih_f;
        const float* bhh = dir ? bhh_b : bhh_f;
        const float br  = bih[ig]         + bhh[ig];
        const float bz  = bih[H + ig]     + bhh[H + ig];
        const float bnx = bih[2 * H + ig];
        const float bnh = bhh[2 * H + ig];
        const bool wout = (t >= CCLIP) && (t < TT - CCLIP);
#pragma unroll
        for (int m = 0; m < 2; ++m) {
#pragma unroll
            for (int r = 0; r < 4; ++r) {
                const int bb = b0 + w32 + m * 16 + lq * 4 + r;
                const float Sr  = acc[m][0][r];
                const float Sz  = acc[m][1][r];
                const float Snx = acc[m][2][r];
                const float Snh = acc[m][3][r];
                const float rg = 1.0f / (1.0f + __expf(-(Sr + br)));
                const float zg = 1.0f / (1.0f + __expf(-(Sz + bz)));
                const float ng = tanhf(Snx + bnx + rg * (Snh + bnh));
                const float hold = bf2f(hin[(size_t)bb * HP + ig]);
                const float hnew = (1.0f - zg) * ng + zg * hold;
                hout[(size_t)bb * HP + ig] = f2bf(hnew);
                if (wout) {
                    const float xv = windows[((size_t)bb * TT + tx) * WINW + ig];
                    out[((size_t)bb * TOUT + (t - CCLIP)) * OUTC + dir * H + ig] = hnew + xv;
                }
            }
        }
    }
}

// ---------------- host ----------------

extern "C" void kernel_launch(void* const* d_in, const int* in_sizes, int n_in,
                              void* d_out, int out_size, void* d_ws, size_t ws_size,
                              hipStream_t stream) {
    const float* windows = (const float*)d_in[0];
    const float* wih_f   = (const float*)d_in[1];
    const float* whh_f   = (const float*)d_in[2];
    const float* bih_f   = (const float*)d_in[3];
    const float* bhh_f   = (const float*)d_in[4];
    const float* wih_b   = (const float*)d_in[5];
    const float* whh_b   = (const float*)d_in[6];
    const float* bih_b   = (const float*)d_in[7];
    const float* bhh_b   = (const float*)d_in[8];
    float* out = (float*)d_out;

    const size_t wbf_sz = (size_t)4 * 2304 * HP * 2;   // 14.2 MB bf16 weights (padded)
    const size_t hbf_sz = (size_t)4 * BB * HP * 2;     // 1.6 MB hidden state (2 dirs x 2 parities)
    if (ws_size < wbf_sz + hbf_sz) return;             // fail cleanly if ws too small

    unsigned short* wbf = (unsigned short*)d_ws;
    unsigned short* hbf = (unsigned short*)((char*)d_ws + wbf_sz);

    zero_h<<<dim3(512), dim3(256), 0, stream>>>(hbf);
    conv_w<<<dim3(2304, 4), dim3(256), 0, stream>>>(wih_f, whh_f, wih_b, whh_b, wbf);

    for (int t = 0; t < TT; ++t) {
        gru_step<<<dim3(48, 2, 2), dim3(256), 0, stream>>>(
            windows, wbf, hbf, bih_f, bhh_f, bih_b, bhh_b, out, t);
    }
}